// Round 2
// baseline (568.457 us; speedup 1.0000x reference)
//
#include <hip/hip_runtime.h>
#include <hip/hip_bf16.h>
#include <stdint.h>

#define M_DIM 4096
#define N_DIM 11008
#define K_DIM 4096
#define KP    (K_DIM / 2)   // packed int32s per weight row

typedef __attribute__((ext_vector_type(4))) float f32x4;
typedef __attribute__((ext_vector_type(8))) short short8;

#define AS1 __attribute__((address_space(1)))
#define AS3 __attribute__((address_space(3)))

static __device__ __forceinline__ unsigned short f32_to_bf16(float f) {
  union { float f; unsigned int u; } v; v.f = f;
  unsigned int r = v.u + (0x7FFFu + ((v.u >> 16) & 1u));  // round-to-nearest-even
  return (unsigned short)(r >> 16);
}

// ---------------- Pass 1: dequant packed int32 nibbles -> W bf16 [N][K] ----------------
__global__ __launch_bounds__(256) void dequant_w(const int* __restrict__ pw,
                                                 const float* __restrict__ sc,
                                                 const float* __restrict__ zp,
                                                 unsigned short* __restrict__ wb) {
  const int total = (N_DIM * KP) / 4;  // 4 int32 -> 8 bf16 per item
  for (int i = blockIdx.x * 256 + threadIdx.x; i < total; i += gridDim.x * 256) {
    int4 p = ((const int4*)pw)[i];
    int row = i >> 9;                  // 512 uint4 per row
    float s = sc[row], z = zp[row];
    int v[4] = {p.x, p.y, p.z, p.w};
    unsigned short o[8];
#pragma unroll
    for (int j = 0; j < 4; ++j) {
      o[2 * j]     = f32_to_bf16(((float)(v[j] & 15) - z) * s);
      o[2 * j + 1] = f32_to_bf16(((float)((v[j] >> 4) & 15) - z) * s);
    }
    uint4 st;
    st.x = (unsigned)o[0] | ((unsigned)o[1] << 16);
    st.y = (unsigned)o[2] | ((unsigned)o[3] << 16);
    st.z = (unsigned)o[4] | ((unsigned)o[5] << 16);
    st.w = (unsigned)o[6] | ((unsigned)o[7] << 16);
    ((uint4*)wb)[i] = st;
  }
}

// ---------------- Pass 2: x fp32 -> bf16 [M][K] ----------------
__global__ __launch_bounds__(256) void conv_x(const float* __restrict__ x,
                                              unsigned short* __restrict__ xb) {
  const int total = (M_DIM * K_DIM) / 8;
  for (int i = blockIdx.x * 256 + threadIdx.x; i < total; i += gridDim.x * 256) {
    float4 a = ((const float4*)x)[2 * i];
    float4 b = ((const float4*)x)[2 * i + 1];
    uint4 st;
    st.x = (unsigned)f32_to_bf16(a.x) | ((unsigned)f32_to_bf16(a.y) << 16);
    st.y = (unsigned)f32_to_bf16(a.z) | ((unsigned)f32_to_bf16(a.w) << 16);
    st.z = (unsigned)f32_to_bf16(b.x) | ((unsigned)f32_to_bf16(b.y) << 16);
    st.w = (unsigned)f32_to_bf16(b.z) | ((unsigned)f32_to_bf16(b.w) << 16);
    ((uint4*)xb)[i] = st;
  }
}

// ---------------- Main: 256x256 tile, BK=32, 4-deep pipelined bf16 MFMA GEMM ----------------
// C[M,N] = Xb[M,K] @ Wb[N,K]^T.  8 waves (2M x 4N), per-wave output 128x64.
// LDS: 4 ring buffers x (A 16KB + B 16KB) = 128 KiB. K-group-major chunk layout
// makes every ds_read_b128 fragment fetch 16 consecutive 16B chunks -> conflict-free.
// One counted vmcnt(8) + one raw s_barrier per K-step (T3+T4); setprio around MFMA (T5).
#define BM 256
#define BN 256
#define BK 32
#define NSTEP (K_DIM / BK)      // 128
#define TILE_US 16384           // ushorts per ring buffer: A[0..8191] | B[8192..16383]
#define NT_M (M_DIM / BM)       // 16
#define NT_N (N_DIM / BN)       // 43
#define NWG  (NT_M * NT_N)      // 688 (div by 8 -> XCD swizzle bijective)

#define WAITV(n) asm volatile("s_waitcnt vmcnt(" #n ")" ::: "memory")
#define BARR     do { __builtin_amdgcn_s_barrier(); asm volatile("" ::: "memory"); } while (0)

__global__ __launch_bounds__(512, 2) void gemm_bt(const unsigned short* __restrict__ Xb,
                                                  const unsigned short* __restrict__ Wb,
                                                  float* __restrict__ C) {
  __shared__ __align__(16) unsigned short lds[4 * TILE_US];  // 128 KiB

  const int t = threadIdx.x;
  const int bid = blockIdx.x;
  const int swz = (bid & 7) * (NWG / 8) + (bid >> 3);  // T1 XCD swizzle (bijective: 688%8==0)
  const int tm = swz & 15;   // M-tile
  const int tn = swz >> 4;   // N-tile (consecutive swz share the W-panel)

  // --- staging: k-group-major chunks. chunk c (0..1023): kgrp=c>>8 (0..3), row=c&255.
  // thread t owns chunks t and t+512 of A, and of B. LDS dst stays linear (base + c*16B),
  // global src is the permuted per-lane address (m104/m173 rule).
  const int c0 = t, c1 = t + 512;
  const unsigned short* aS0 = Xb + (size_t)(tm * BM + (c0 & 255)) * K_DIM + ((c0 >> 8) * 8);
  const unsigned short* aS1 = Xb + (size_t)(tm * BM + (c1 & 255)) * K_DIM + ((c1 >> 8) * 8);
  const unsigned short* bS0 = Wb + (size_t)(tn * BN + (c0 & 255)) * K_DIM + ((c0 >> 8) * 8);
  const unsigned short* bS1 = Wb + (size_t)(tn * BN + (c1 & 255)) * K_DIM + ((c1 >> 8) * 8);
  const int aD0 = c0 * 8, aD1 = c1 * 8;
  const int bD0 = 8192 + c0 * 8, bD1 = 8192 + c1 * 8;

  // --- wave / lane geometry
  const int lane = t & 63;
  const int w = t >> 6;
  const int wm = w >> 2;          // 0..1 -> rows wm*128 .. +127
  const int wn = w & 3;           // 0..3 -> cols wn*64 .. +63
  const int lr = lane & 15, lk = lane >> 4;

  // fragment read bases (ushort units within a ring buffer)
  // A frag m: chunk (lk, wm*128 + m*16 + lr) ; B frag n: chunk (lk, wn*64 + n*16 + lr)
  const int aro0 = (lk * 256 + wm * 128 + lr) * 8;          // + m*128
  const int bro0 = 8192 + (lk * 256 + wn * 64 + lr) * 8;    // + n*128

  f32x4 acc[8][4] = {};

#define STAGE(T) do {                                                                   \
    unsigned short* dbase = lds + (((T) & 3) * TILE_US);                                \
    const size_t ko = (size_t)(T) * BK;                                                 \
    __builtin_amdgcn_global_load_lds((const AS1 void*)(aS0 + ko), (AS3 void*)(dbase + aD0), 16, 0, 0); \
    __builtin_amdgcn_global_load_lds((const AS1 void*)(aS1 + ko), (AS3 void*)(dbase + aD1), 16, 0, 0); \
    __builtin_amdgcn_global_load_lds((const AS1 void*)(bS0 + ko), (AS3 void*)(dbase + bD0), 16, 0, 0); \
    __builtin_amdgcn_global_load_lds((const AS1 void*)(bS1 + ko), (AS3 void*)(dbase + bD1), 16, 0, 0); \
  } while (0)

#define COMPUTE(T) do {                                                                 \
    const unsigned short* cbase = lds + (((T) & 3) * TILE_US);                          \
    short8 af[8], bf[4];                                                                \
    _Pragma("unroll") for (int m = 0; m < 8; ++m)                                       \
      af[m] = *(const short8*)(cbase + aro0 + m * 128);                                 \
    _Pragma("unroll") for (int n = 0; n < 4; ++n)                                       \
      bf[n] = *(const short8*)(cbase + bro0 + n * 128);                                 \
    __builtin_amdgcn_s_setprio(1);                                                      \
    _Pragma("unroll") for (int m = 0; m < 8; ++m)                                       \
      _Pragma("unroll") for (int n = 0; n < 4; ++n)                                     \
        acc[m][n] = __builtin_amdgcn_mfma_f32_16x16x32_bf16(af[m], bf[n], acc[m][n], 0, 0, 0); \
    __builtin_amdgcn_s_setprio(0);                                                      \
  } while (0)

  // prologue: 3 tiles in flight
  STAGE(0); STAGE(1); STAGE(2);

  // steady state: wait (counted, never 0), barrier, stage t+3, read+MFMA tile t.
  // vmcnt(8) leaves tiles t+2,t+3 in flight -> tile t (and t+1) complete.
  for (int T = 0; T < NSTEP - 3; ++T) {
    WAITV(8); BARR;
    STAGE(T + 3);
    COMPUTE(T);
  }
  // peeled tail: drain 8 -> 4 -> 0
  WAITV(8); BARR; COMPUTE(NSTEP - 3);
  WAITV(4); BARR; COMPUTE(NSTEP - 2);
  WAITV(0); BARR; COMPUTE(NSTEP - 1);

#undef STAGE
#undef COMPUTE

  // epilogue: C/D layout col=lane&15, row=(lane>>4)*4+reg (validated round 1)
  const int row0 = tm * BM + wm * 128 + lk * 4;
  const int col0 = tn * BN + wn * 64 + lr;
#pragma unroll
  for (int m = 0; m < 8; ++m)
#pragma unroll
    for (int n = 0; n < 4; ++n)
#pragma unroll
      for (int rr = 0; rr < 4; ++rr)
        C[(size_t)(row0 + m * 16 + rr) * N_DIM + col0 + n * 16] = acc[m][n][rr];
}

// ---------------- Fallback: fp32 LDS-tiled GEMM reading packed weights (ws too small) ----------------
__global__ __launch_bounds__(256) void fallback_gemm(const float* __restrict__ x,
                                                     const int* __restrict__ pw,
                                                     const float* __restrict__ sc,
                                                     const float* __restrict__ zp,
                                                     float* __restrict__ out) {
  __shared__ float Xs[64][33];
  __shared__ float Ws[64][33];
  const int bid = blockIdx.x;
  const int bm = bid & 63;
  const int bn = bid >> 6;
  const int t = threadIdx.x;
  const int tx = t & 15, ty = t >> 4;
  float acc[4][4] = {};
  for (int k0 = 0; k0 < K_DIM; k0 += 32) {
    __syncthreads();
#pragma unroll
    for (int i = 0; i < 8; ++i) {
      int e = t + i * 256; int r = e >> 5, c = e & 31;
      Xs[r][c] = x[(size_t)(bm * 64 + r) * K_DIM + k0 + c];
    }
#pragma unroll
    for (int i = 0; i < 4; ++i) {
      int e = t + i * 256; int rr = e >> 4, jj = e & 15;
      int row = bn * 64 + rr;
      int v = pw[(size_t)row * KP + (k0 >> 1) + jj];
      float s = sc[row], z = zp[row];
      Ws[rr][2 * jj]     = ((float)(v & 15) - z) * s;
      Ws[rr][2 * jj + 1] = ((float)((v >> 4) & 15) - z) * s;
    }
    __syncthreads();
#pragma unroll
    for (int kk = 0; kk < 32; ++kk) {
      float a[4], b[4];
#pragma unroll
      for (int i2 = 0; i2 < 4; ++i2) a[i2] = Xs[ty * 4 + i2][kk];
#pragma unroll
      for (int j2 = 0; j2 < 4; ++j2) b[j2] = Ws[tx * 4 + j2][kk];
#pragma unroll
      for (int i2 = 0; i2 < 4; ++i2)
#pragma unroll
        for (int j2 = 0; j2 < 4; ++j2) acc[i2][j2] += a[i2] * b[j2];
    }
  }
#pragma unroll
  for (int i2 = 0; i2 < 4; ++i2)
#pragma unroll
    for (int j2 = 0; j2 < 4; ++j2)
      out[(size_t)(bm * 64 + ty * 4 + i2) * N_DIM + bn * 64 + tx * 4 + j2] = acc[i2][j2];
}

extern "C" void kernel_launch(void* const* d_in, const int* in_sizes, int n_in,
                              void* d_out, int out_size, void* d_ws, size_t ws_size,
                              hipStream_t stream) {
  const float* x  = (const float*)d_in[0];
  const int*   pw = (const int*)d_in[1];
  const float* sc = (const float*)d_in[2];
  const float* zp = (const float*)d_in[3];
  float* out = (float*)d_out;

  const size_t wb_bytes = (size_t)N_DIM * K_DIM * 2;
  const size_t xb_bytes = (size_t)M_DIM * K_DIM * 2;

  if (ws_size >= wb_bytes + xb_bytes) {
    unsigned short* wb = (unsigned short*)d_ws;
    unsigned short* xb = (unsigned short*)((char*)d_ws + wb_bytes);
    hipLaunchKernelGGL(dequant_w, dim3(2048), dim3(256), 0, stream, pw, sc, zp, wb);
    hipLaunchKernelGGL(conv_x,    dim3(2048), dim3(256), 0, stream, x, xb);
    hipLaunchKernelGGL(gemm_bt,   dim3(NWG),  dim3(512), 0, stream, xb, wb, out);
  } else {
    hipLaunchKernelGGL(fallback_gemm, dim3(64 * 172), dim3(256), 0, stream, x, pw, sc, zp, out);
  }
}

// Round 3
// 485.110 us; speedup vs baseline: 1.1718x; 1.1718x over previous
//
#include <hip/hip_runtime.h>
#include <hip/hip_bf16.h>
#include <stdint.h>

#define M_DIM 4096
#define N_DIM 11008
#define K_DIM 4096
#define KP    (K_DIM / 2)   // packed int32s per weight row

typedef __attribute__((ext_vector_type(4))) float f32x4;
typedef __attribute__((ext_vector_type(8))) short short8;

#define AS1 __attribute__((address_space(1)))
#define AS3 __attribute__((address_space(3)))

static __device__ __forceinline__ unsigned short f32_to_bf16(float f) {
  union { float f; unsigned int u; } v; v.f = f;
  unsigned int r = v.u + (0x7FFFu + ((v.u >> 16) & 1u));  // round-to-nearest-even
  return (unsigned short)(r >> 16);
}

// ---------------- Pass 1: dequant packed int32 nibbles -> W bf16 [N][K] ----------------
__global__ __launch_bounds__(256) void dequant_w(const int* __restrict__ pw,
                                                 const float* __restrict__ sc,
                                                 const float* __restrict__ zp,
                                                 unsigned short* __restrict__ wb) {
  const int total = (N_DIM * KP) / 4;  // 4 int32 -> 8 bf16 per item
  for (int i = blockIdx.x * 256 + threadIdx.x; i < total; i += gridDim.x * 256) {
    int4 p = ((const int4*)pw)[i];
    int row = i >> 9;                  // 512 uint4 per row
    float s = sc[row], z = zp[row];
    int v[4] = {p.x, p.y, p.z, p.w};
    unsigned short o[8];
#pragma unroll
    for (int j = 0; j < 4; ++j) {
      o[2 * j]     = f32_to_bf16(((float)(v[j] & 15) - z) * s);
      o[2 * j + 1] = f32_to_bf16(((float)((v[j] >> 4) & 15) - z) * s);
    }
    uint4 st;
    st.x = (unsigned)o[0] | ((unsigned)o[1] << 16);
    st.y = (unsigned)o[2] | ((unsigned)o[3] << 16);
    st.z = (unsigned)o[4] | ((unsigned)o[5] << 16);
    st.w = (unsigned)o[6] | ((unsigned)o[7] << 16);
    ((uint4*)wb)[i] = st;
  }
}

// ---------------- Pass 2: x fp32 -> bf16 [M][K] ----------------
__global__ __launch_bounds__(256) void conv_x(const float* __restrict__ x,
                                              unsigned short* __restrict__ xb) {
  const int total = (M_DIM * K_DIM) / 8;
  for (int i = blockIdx.x * 256 + threadIdx.x; i < total; i += gridDim.x * 256) {
    float4 a = ((const float4*)x)[2 * i];
    float4 b = ((const float4*)x)[2 * i + 1];
    uint4 st;
    st.x = (unsigned)f32_to_bf16(a.x) | ((unsigned)f32_to_bf16(a.y) << 16);
    st.y = (unsigned)f32_to_bf16(a.z) | ((unsigned)f32_to_bf16(a.w) << 16);
    st.z = (unsigned)f32_to_bf16(b.x) | ((unsigned)f32_to_bf16(b.y) << 16);
    st.w = (unsigned)f32_to_bf16(b.z) | ((unsigned)f32_to_bf16(b.w) << 16);
    ((uint4*)xb)[i] = st;
  }
}

// ---------------- Main: 256x256 tile, BK=64, 8-phase pipelined bf16 MFMA GEMM (m201 port) ----------------
// C[M,N] = Xb[M,K] @ Wb[N,K]^T.  8 waves (2M x 4N), per-wave output 128x64.
// LDS: 8 half-slots x 16 KiB = 128 KiB: slot (parity p, role r): r0=B-half0, r1=B-half1,
// r2=A-half0, r3=A-half1. Within a half: chunk c (0..1023) = kgrp(c>>7)*128 + row(c&127),
// stored at ushort offset c*8 -> conflict-free ds_read_b128 (verified 0 conflicts in R2)
// AND linear global_load_lds destinations (m104 rule; source is per-lane permuted).
// Stage stream runs 6 halves ahead of consumption. Per K-tile (4 phases):
//   P1: read A(m0-3,kk0)+B(:,kk0) [8 rd]; stage A0(tile+1); BAR; 16 MFMA; BAR
//   P2: read A(m4-7,kk0)+B(:,kk1) [8 rd]; stage A1(tile+1); BAR; 16 MFMA; BAR
//   P3: read A(m0-3,kk1)          [4 rd]; stage B0(tile+2); BAR; 16 MFMA; BAR
//   P4: read A(m4-7,kk1)          [4 rd]; stage B1(tile+2); vmcnt(4); BAR; 16 MFMA; BAR
// Invariants: vmcnt(4) at P4 of tile t-1 leaves only B(t+1) outstanding -> all of tile t
// resident before its P1 reads. B-halves last read at P2, overwritten at P3/P4 (barrier-
// separated); A-halves last read P4, overwritten at next tile's P1/P2.
#define BM 256
#define BN 256
#define BK 64
#define NTILE (K_DIM / BK)      // 64
#define NT_M (M_DIM / BM)       // 16
#define NT_N (N_DIM / BN)       // 43
#define NWG  (NT_M * NT_N)      // 688 (div by 8 -> XCD swizzle bijective)

#define WAITV(n) asm volatile("s_waitcnt vmcnt(" #n ")" ::: "memory")
#define BARR     do { asm volatile("" ::: "memory"); __builtin_amdgcn_s_barrier(); asm volatile("" ::: "memory"); } while (0)

__global__ __launch_bounds__(512, 2) void gemm_bt(const unsigned short* __restrict__ Xb,
                                                  const unsigned short* __restrict__ Wb,
                                                  float* __restrict__ C) {
  __shared__ __align__(16) unsigned short lds[65536];  // 128 KiB, 8 x 8192-ushort half-slots

  const int t = threadIdx.x;
  const int bid = blockIdx.x;
  const int swz = (bid & 7) * (NWG / 8) + (bid >> 3);  // T1 XCD swizzle
  const int tm = swz & 15;   // M-tile
  const int tn = swz >> 4;   // N-tile (consecutive swz share the W-panel)

  // --- stage sources: thread t owns chunks t and t+512 of each half (2 x 16B loads).
  // chunk c: kgrp = c>>7 (k = kgrp*8..+7), row = c&127.
  const int r0 = t & 127,          k0 = (t >> 7) * 8;          // chunk t
  const int r1 = (t + 512) & 127,  k1 = ((t + 512) >> 7) * 8;  // chunk t+512
  const unsigned short* pB0c0 = Wb + (size_t)(tn * BN + r0) * K_DIM + k0;
  const unsigned short* pB0c1 = Wb + (size_t)(tn * BN + r1) * K_DIM + k1;
  const unsigned short* pB1c0 = Wb + (size_t)(tn * BN + 128 + r0) * K_DIM + k0;
  const unsigned short* pB1c1 = Wb + (size_t)(tn * BN + 128 + r1) * K_DIM + k1;
  const unsigned short* pA0c0 = Xb + (size_t)(tm * BM + r0) * K_DIM + k0;
  const unsigned short* pA0c1 = Xb + (size_t)(tm * BM + r1) * K_DIM + k1;
  const unsigned short* pA1c0 = Xb + (size_t)(tm * BM + 128 + r0) * K_DIM + k0;
  const unsigned short* pA1c1 = Xb + (size_t)(tm * BM + 128 + r1) * K_DIM + k1;
  const int d0 = t * 8;            // LDS ushort offset of chunk t within a half-slot
  const int d1 = d0 + 4096;        // chunk t+512

  // --- wave / lane geometry
  const int lane = t & 63;
  const int w = t >> 6;
  const int wm = w >> 2;          // 0..1 -> rows wm*128..+127  (A-half = wm)
  const int wn = w & 3;           // 0..3 -> cols wn*64..+63    (B-half = wn>>1)
  const int lr = lane & 15, lk = lane >> 4;

  // fragment read bases (ushort units). Full addr = base + P*32768 + kk*4096 + frag*128.
  const int aB = (2 + wm) * 8192 + lk * 1024 + lr * 8;
  const int bB = (wn >> 1) * 8192 + lk * 1024 + (wn & 1) * 512 + lr * 8;

  f32x4 acc[8][4] = {};

#define GLL(src, dstoff) \
  __builtin_amdgcn_global_load_lds((const AS1 void*)(src), (AS3 void*)(lds + (dstoff)), 16, 0, 0)

  // ---- prologue: stage 6 halves: B0,B1,A0,A1 of tile0 (parity0), B0,B1 of tile1 (parity1)
  GLL(pB0c0, 0 * 8192 + d0); GLL(pB0c1, 0 * 8192 + d1);
  GLL(pB1c0, 1 * 8192 + d0); GLL(pB1c1, 1 * 8192 + d1);
  GLL(pA0c0, 2 * 8192 + d0); GLL(pA0c1, 2 * 8192 + d1);
  GLL(pA1c0, 3 * 8192 + d0); GLL(pA1c1, 3 * 8192 + d1);
  GLL(pB0c0 + BK, 4 * 8192 + d0); GLL(pB0c1 + BK, 4 * 8192 + d1);
  GLL(pB1c0 + BK, 5 * 8192 + d0); GLL(pB1c1 + BK, 5 * 8192 + d1);
  pB0c0 += 2 * BK; pB0c1 += 2 * BK; pB1c0 += 2 * BK; pB1c1 += 2 * BK;  // next B stage: tile 2
  pA0c0 += BK;     pA0c1 += BK;     pA1c0 += BK;     pA1c1 += BK;      // next A stage: tile 1
  WAITV(4);  // retire halves 0..3 (all of tile 0); B(tile1) stays in flight
  BARR;

  // VMODE: 0 -> vmcnt(4), 1 -> vmcnt(0), 2 -> none
#define TILE(P, SA, SB, VMODE) do {                                                        \
    short8 af[4], bf0[4], bf1[4];                                                          \
    /* ---- P1 ---- */                                                                     \
    _Pragma("unroll") for (int i = 0; i < 4; ++i)                                          \
      af[i] = *(const short8*)(lds + (P) * 32768 + aB + i * 128);                          \
    _Pragma("unroll") for (int n = 0; n < 4; ++n)                                          \
      bf0[n] = *(const short8*)(lds + (P) * 32768 + bB + n * 128);                         \
    if (SA) { GLL(pA0c0, (((P) ^ 1) * 4 + 2) * 8192 + d0);                                 \
              GLL(pA0c1, (((P) ^ 1) * 4 + 2) * 8192 + d1);                                 \
              pA0c0 += BK; pA0c1 += BK; }                                                  \
    BARR;                                                                                  \
    __builtin_amdgcn_s_setprio(1);                                                         \
    _Pragma("unroll") for (int i = 0; i < 4; ++i)                                          \
      _Pragma("unroll") for (int n = 0; n < 4; ++n)                                        \
        acc[i][n] = __builtin_amdgcn_mfma_f32_16x16x32_bf16(af[i], bf0[n], acc[i][n], 0, 0, 0); \
    __builtin_amdgcn_s_setprio(0);                                                         \
    BARR;                                                                                  \
    /* ---- P2 ---- */                                                                     \
    _Pragma("unroll") for (int i = 0; i < 4; ++i)                                          \
      af[i] = *(const short8*)(lds + (P) * 32768 + aB + (4 + i) * 128);                    \
    _Pragma("unroll") for (int n = 0; n < 4; ++n)                                          \
      bf1[n] = *(const short8*)(lds + (P) * 32768 + bB + 4096 + n * 128);                  \
    if (SA) { GLL(pA1c0, (((P) ^ 1) * 4 + 3) * 8192 + d0);                                 \
              GLL(pA1c1, (((P) ^ 1) * 4 + 3) * 8192 + d1);                                 \
              pA1c0 += BK; pA1c1 += BK; }                                                  \
    BARR;                                                                                  \
    __builtin_amdgcn_s_setprio(1);                                                         \
    _Pragma("unroll") for (int i = 0; i < 4; ++i)                                          \
      _Pragma("unroll") for (int n = 0; n < 4; ++n)                                        \
        acc[4 + i][n] = __builtin_amdgcn_mfma_f32_16x16x32_bf16(af[i], bf0[n], acc[4 + i][n], 0, 0, 0); \
    __builtin_amdgcn_s_setprio(0);                                                         \
    BARR;                                                                                  \
    /* ---- P3 ---- */                                                                     \
    _Pragma("unroll") for (int i = 0; i < 4; ++i)                                          \
      af[i] = *(const short8*)(lds + (P) * 32768 + aB + 4096 + i * 128);                   \
    if (SB) { GLL(pB0c0, ((P) * 4 + 0) * 8192 + d0);                                       \
              GLL(pB0c1, ((P) * 4 + 0) * 8192 + d1);                                       \
              pB0c0 += BK; pB0c1 += BK; }                                                  \
    BARR;                                                                                  \
    __builtin_amdgcn_s_setprio(1);                                                         \
    _Pragma("unroll") for (int i = 0; i < 4; ++i)                                          \
      _Pragma("unroll") for (int n = 0; n < 4; ++n)                                        \
        acc[i][n] = __builtin_amdgcn_mfma_f32_16x16x32_bf16(af[i], bf1[n], acc[i][n], 0, 0, 0); \
    __builtin_amdgcn_s_setprio(0);                                                         \
    BARR;                                                                                  \
    /* ---- P4 ---- */                                                                     \
    _Pragma("unroll") for (int i = 0; i < 4; ++i)                                          \
      af[i] = *(const short8*)(lds + (P) * 32768 + aB + 4096 + (4 + i) * 128);             \
    if (SB) { GLL(pB1c0, ((P) * 4 + 1) * 8192 + d0);                                       \
              GLL(pB1c1, ((P) * 4 + 1) * 8192 + d1);                                       \
              pB1c0 += BK; pB1c1 += BK; }                                                  \
    if ((VMODE) == 0) { WAITV(4); } else if ((VMODE) == 1) { WAITV(0); }                   \
    BARR;                                                                                  \
    __builtin_amdgcn_s_setprio(1);                                                         \
    _Pragma("unroll") for (int i = 0; i < 4; ++i)                                          \
      _Pragma("unroll") for (int n = 0; n < 4; ++n)                                        \
        acc[4 + i][n] = __builtin_amdgcn_mfma_f32_16x16x32_bf16(af[i], bf1[n], acc[4 + i][n], 0, 0, 0); \
    __builtin_amdgcn_s_setprio(0);                                                         \
    BARR;                                                                                  \
  } while (0)

  // main loop: tiles 0..61
  for (int it = 0; it < (NTILE - 2) / 2; ++it) {
    TILE(0, 1, 1, 0);
    TILE(1, 1, 1, 0);
  }
  TILE(0, 1, 0, 1);   // tile 62: stage A(63) only; drain everything
  TILE(1, 0, 0, 2);   // tile 63: no stage, no wait

#undef TILE
#undef GLL

  // epilogue: C/D layout col=lane&15, row=(lane>>4)*4+reg (validated R1/R2)
  const int row0 = tm * BM + wm * 128 + lk * 4;
  const int col0 = tn * BN + wn * 64 + lr;
#pragma unroll
  for (int m = 0; m < 8; ++m)
#pragma unroll
    for (int n = 0; n < 4; ++n)
#pragma unroll
      for (int rr = 0; rr < 4; ++rr)
        C[(size_t)(row0 + m * 16 + rr) * N_DIM + col0 + n * 16] = acc[m][n][rr];
}

// ---------------- Fallback: fp32 LDS-tiled GEMM reading packed weights (ws too small) ----------------
__global__ __launch_bounds__(256) void fallback_gemm(const float* __restrict__ x,
                                                     const int* __restrict__ pw,
                                                     const float* __restrict__ sc,
                                                     const float* __restrict__ zp,
                                                     float* __restrict__ out) {
  __shared__ float Xs[64][33];
  __shared__ float Ws[64][33];
  const int bid = blockIdx.x;
  const int bm = bid & 63;
  const int bn = bid >> 6;
  const int t = threadIdx.x;
  const int tx = t & 15, ty = t >> 4;
  float acc[4][4] = {};
  for (int k0 = 0; k0 < K_DIM; k0 += 32) {
    __syncthreads();
#pragma unroll
    for (int i = 0; i < 8; ++i) {
      int e = t + i * 256; int r = e >> 5, c = e & 31;
      Xs[r][c] = x[(size_t)(bm * 64 + r) * K_DIM + k0 + c];
    }
#pragma unroll
    for (int i = 0; i < 4; ++i) {
      int e = t + i * 256; int rr = e >> 4, jj = e & 15;
      int row = bn * 64 + rr;
      int v = pw[(size_t)row * KP + (k0 >> 1) + jj];
      float s = sc[row], z = zp[row];
      Ws[rr][2 * jj]     = ((float)(v & 15) - z) * s;
      Ws[rr][2 * jj + 1] = ((float)((v >> 4) & 15) - z) * s;
    }
    __syncthreads();
#pragma unroll
    for (int kk = 0; kk < 32; ++kk) {
      float a[4], b[4];
#pragma unroll
      for (int i2 = 0; i2 < 4; ++i2) a[i2] = Xs[ty * 4 + i2][kk];
#pragma unroll
      for (int j2 = 0; j2 < 4; ++j2) b[j2] = Ws[tx * 4 + j2][kk];
#pragma unroll
      for (int i2 = 0; i2 < 4; ++i2)
#pragma unroll
        for (int j2 = 0; j2 < 4; ++j2) acc[i2][j2] += a[i2] * b[j2];
    }
  }
#pragma unroll
  for (int i2 = 0; i2 < 4; ++i2)
#pragma unroll
    for (int j2 = 0; j2 < 4; ++j2)
      out[(size_t)(bm * 64 + ty * 4 + i2) * N_DIM + bn * 64 + tx * 4 + j2] = acc[i2][j2];
}

extern "C" void kernel_launch(void* const* d_in, const int* in_sizes, int n_in,
                              void* d_out, int out_size, void* d_ws, size_t ws_size,
                              hipStream_t stream) {
  const float* x  = (const float*)d_in[0];
  const int*   pw = (const int*)d_in[1];
  const float* sc = (const float*)d_in[2];
  const float* zp = (const float*)d_in[3];
  float* out = (float*)d_out;

  const size_t wb_bytes = (size_t)N_DIM * K_DIM * 2;
  const size_t xb_bytes = (size_t)M_DIM * K_DIM * 2;

  if (ws_size >= wb_bytes + xb_bytes) {
    unsigned short* wb = (unsigned short*)d_ws;
    unsigned short* xb = (unsigned short*)((char*)d_ws + wb_bytes);
    hipLaunchKernelGGL(dequant_w, dim3(2048), dim3(256), 0, stream, pw, sc, zp, wb);
    hipLaunchKernelGGL(conv_x,    dim3(2048), dim3(256), 0, stream, x, xb);
    hipLaunchKernelGGL(gemm_bt,   dim3(NWG),  dim3(512), 0, stream, xb, wb, out);
  } else {
    hipLaunchKernelGGL(fallback_gemm, dim3(64 * 172), dim3(256), 0, stream, x, pw, sc, zp, out);
  }
}

// Round 4
// 374.506 us; speedup vs baseline: 1.5179x; 1.2953x over previous
//
#include <hip/hip_runtime.h>
#include <hip/hip_bf16.h>
#include <stdint.h>

#define M_DIM 4096
#define N_DIM 11008
#define K_DIM 4096
#define KP    (K_DIM / 2)   // packed int32s per weight row

typedef __attribute__((ext_vector_type(4))) float f32x4;
typedef __attribute__((ext_vector_type(8))) short short8;

#define AS1 __attribute__((address_space(1)))
#define AS3 __attribute__((address_space(3)))

static __device__ __forceinline__ unsigned short f32_to_bf16(float f) {
  union { float f; unsigned int u; } v; v.f = f;
  unsigned int r = v.u + (0x7FFFu + ((v.u >> 16) & 1u));  // round-to-nearest-even
  return (unsigned short)(r >> 16);
}

// ---------------- Pass 1: dequant packed int32 nibbles -> W bf16 [N][K] ----------------
__global__ __launch_bounds__(256) void dequant_w(const int* __restrict__ pw,
                                                 const float* __restrict__ sc,
                                                 const float* __restrict__ zp,
                                                 unsigned short* __restrict__ wb) {
  const int total = (N_DIM * KP) / 4;  // 4 int32 -> 8 bf16 per item
  for (int i = blockIdx.x * 256 + threadIdx.x; i < total; i += gridDim.x * 256) {
    int4 p = ((const int4*)pw)[i];
    int row = i >> 9;                  // 512 uint4 per row
    float s = sc[row], z = zp[row];
    int v[4] = {p.x, p.y, p.z, p.w};
    unsigned short o[8];
#pragma unroll
    for (int j = 0; j < 4; ++j) {
      o[2 * j]     = f32_to_bf16(((float)(v[j] & 15) - z) * s);
      o[2 * j + 1] = f32_to_bf16(((float)((v[j] >> 4) & 15) - z) * s);
    }
    uint4 st;
    st.x = (unsigned)o[0] | ((unsigned)o[1] << 16);
    st.y = (unsigned)o[2] | ((unsigned)o[3] << 16);
    st.z = (unsigned)o[4] | ((unsigned)o[5] << 16);
    st.w = (unsigned)o[6] | ((unsigned)o[7] << 16);
    ((uint4*)wb)[i] = st;
  }
}

// ---------------- Pass 2: x fp32 -> bf16 [M][K] ----------------
__global__ __launch_bounds__(256) void conv_x(const float* __restrict__ x,
                                              unsigned short* __restrict__ xb) {
  const int total = (M_DIM * K_DIM) / 8;
  for (int i = blockIdx.x * 256 + threadIdx.x; i < total; i += gridDim.x * 256) {
    float4 a = ((const float4*)x)[2 * i];
    float4 b = ((const float4*)x)[2 * i + 1];
    uint4 st;
    st.x = (unsigned)f32_to_bf16(a.x) | ((unsigned)f32_to_bf16(a.y) << 16);
    st.y = (unsigned)f32_to_bf16(a.z) | ((unsigned)f32_to_bf16(a.w) << 16);
    st.z = (unsigned)f32_to_bf16(b.x) | ((unsigned)f32_to_bf16(b.y) << 16);
    st.w = (unsigned)f32_to_bf16(b.z) | ((unsigned)f32_to_bf16(b.w) << 16);
    ((uint4*)xb)[i] = st;
  }
}

// ---------------- Main: 256x256 tile, BK=64, 8-phase pipelined bf16 MFMA GEMM ----------------
// C[M,N] = Xb[M,K] @ Wb[N,K]^T.  8 waves (2M x 4N), per-wave output 128x64.
// LDS: 8 half-slots x 16 KiB: slot = parity*4 + role {0:B0,1:B1,2:A0,3:A1}.
// Half layout: row-major [128 rows][64 k] bf16 with 16B-chunk XOR swizzle:
//   LDS slot (row, j) holds global chunk (row, j ^ (row&7)).   (involution)
// -> staging: LDS dst linear (m104), global src pre-swizzled per-lane; a wave covers
//    8 consecutive rows x 128 B contiguous each => fully coalesced (R3's scatter fixed).
// -> reads: fragment (row, g=kk*4+lk) at slot j=g^(lr&7); per 16 lanes each 16B slot
//    hit exactly twice => 2 lanes/bank = free (m136).
// Schedule (frozen from R3): per K-tile 4 phases; stage A(t+1) at P1/P2, B(t+2) at P3/P4;
// vmcnt(4) once per K-tile at P4 (never 0 in main loop); 2 barriers/phase; setprio(1) on MFMA.
#define BM 256
#define BN 256
#define BK 64
#define NTILE (K_DIM / BK)      // 64
#define NT_M (M_DIM / BM)       // 16
#define NT_N (N_DIM / BN)       // 43
#define NWG  (NT_M * NT_N)      // 688 (div by 8 -> XCD swizzle bijective)

#define WAITV(n) asm volatile("s_waitcnt vmcnt(" #n ")" ::: "memory")
#define BARR     do { asm volatile("" ::: "memory"); __builtin_amdgcn_s_barrier(); asm volatile("" ::: "memory"); } while (0)

__global__ __launch_bounds__(512, 2) void gemm_bt(const unsigned short* __restrict__ Xb,
                                                  const unsigned short* __restrict__ Wb,
                                                  float* __restrict__ C) {
  __shared__ __align__(16) unsigned short lds[65536];  // 128 KiB, 8 x 8192-ushort half-slots

  const int t = threadIdx.x;
  const int bid = blockIdx.x;
  const int swz = (bid & 7) * (NWG / 8) + (bid >> 3);  // T1 XCD swizzle
  const int tm = swz & 15;   // M-tile
  const int tn = swz >> 4;   // N-tile (consecutive swz share the W-panel)

  // --- stage sources: thread t owns LDS chunks c0=t (rows 0..63) and c1=t+512 (rows 64..127)
  // of each half. row = c>>3, slot j = c&7, global chunk g = j ^ (row&7)  (c1: same g, row+64).
  const int srow = t >> 3;                       // 0..63
  const int g0 = (t & 7) ^ (srow & 7);           // pre-swizzled global chunk
  const int koff = g0 * 8;                       // ushort offset within K-tile
  const unsigned short* pB0c0 = Wb + (size_t)(tn * BN + srow) * K_DIM + koff;
  const unsigned short* pB0c1 = Wb + (size_t)(tn * BN + 64 + srow) * K_DIM + koff;
  const unsigned short* pB1c0 = Wb + (size_t)(tn * BN + 128 + srow) * K_DIM + koff;
  const unsigned short* pB1c1 = Wb + (size_t)(tn * BN + 192 + srow) * K_DIM + koff;
  const unsigned short* pA0c0 = Xb + (size_t)(tm * BM + srow) * K_DIM + koff;
  const unsigned short* pA0c1 = Xb + (size_t)(tm * BM + 64 + srow) * K_DIM + koff;
  const unsigned short* pA1c0 = Xb + (size_t)(tm * BM + 128 + srow) * K_DIM + koff;
  const unsigned short* pA1c1 = Xb + (size_t)(tm * BM + 192 + srow) * K_DIM + koff;
  const int d0 = t * 8;            // LDS ushort offset of chunk c0 within a half-slot (linear)
  const int d1 = d0 + 4096;        // chunk c1

  // --- wave / lane geometry
  const int lane = t & 63;
  const int w = t >> 6;
  const int wm = w >> 2;          // 0..1 -> rows wm*128..+127  (A-half = wm)
  const int wn = w & 3;           // 0..3 -> cols wn*64..+63    (B-half = wn>>1)
  const int lr = lane & 15, lk = lane >> 4;

  // fragment read bases (ushort units within the 8-slot LDS; add P*32768 + mloc/n*1024).
  // addr = halfbase + row*64 + j*8, row = mloc*16+lr, j = (kk*4+lk) ^ (lr&7).
  const int j0 = lk ^ (lr & 7);
  const int aB0 = (2 + wm) * 8192 + lr * 64 + j0 * 8;  // kk=0
  const int aB1 = aB0 ^ 32;                            // kk=1 (j ^= 4)
  const int bB0 = (wn >> 1) * 8192 + (wn & 1) * 4096 + lr * 64 + j0 * 8;
  const int bB1 = bB0 ^ 32;

  f32x4 acc[8][4] = {};

#define GLL(src, dstoff) \
  __builtin_amdgcn_global_load_lds((const AS1 void*)(src), (AS3 void*)(lds + (dstoff)), 16, 0, 0)

  // ---- prologue: stage 6 halves: B0,B1,A0,A1 of tile0 (parity0), B0,B1 of tile1 (parity1)
  GLL(pB0c0, 0 * 8192 + d0); GLL(pB0c1, 0 * 8192 + d1);
  GLL(pB1c0, 1 * 8192 + d0); GLL(pB1c1, 1 * 8192 + d1);
  GLL(pA0c0, 2 * 8192 + d0); GLL(pA0c1, 2 * 8192 + d1);
  GLL(pA1c0, 3 * 8192 + d0); GLL(pA1c1, 3 * 8192 + d1);
  GLL(pB0c0 + BK, 4 * 8192 + d0); GLL(pB0c1 + BK, 4 * 8192 + d1);
  GLL(pB1c0 + BK, 5 * 8192 + d0); GLL(pB1c1 + BK, 5 * 8192 + d1);
  pB0c0 += 2 * BK; pB0c1 += 2 * BK; pB1c0 += 2 * BK; pB1c1 += 2 * BK;  // next B stage: tile 2
  pA0c0 += BK;     pA0c1 += BK;     pA1c0 += BK;     pA1c1 += BK;      // next A stage: tile 1
  WAITV(4);  // retire halves 0..3 (all of tile 0); B(tile1) stays in flight
  BARR;

  // VMODE: 0 -> vmcnt(4), 1 -> vmcnt(0), 2 -> none
#define TILE(P, SA, SB, VMODE) do {                                                        \
    short8 af[4], bf0[4], bf1[4];                                                          \
    /* ---- P1: A rows 0-63 kk0, B kk0 ---- */                                             \
    _Pragma("unroll") for (int i = 0; i < 4; ++i)                                          \
      af[i] = *(const short8*)(lds + (P) * 32768 + aB0 + i * 1024);                        \
    _Pragma("unroll") for (int n = 0; n < 4; ++n)                                          \
      bf0[n] = *(const short8*)(lds + (P) * 32768 + bB0 + n * 1024);                       \
    if (SA) { GLL(pA0c0, (((P) ^ 1) * 4 + 2) * 8192 + d0);                                 \
              GLL(pA0c1, (((P) ^ 1) * 4 + 2) * 8192 + d1);                                 \
              pA0c0 += BK; pA0c1 += BK; }                                                  \
    BARR;                                                                                  \
    __builtin_amdgcn_s_setprio(1);                                                         \
    _Pragma("unroll") for (int i = 0; i < 4; ++i)                                          \
      _Pragma("unroll") for (int n = 0; n < 4; ++n)                                        \
        acc[i][n] = __builtin_amdgcn_mfma_f32_16x16x32_bf16(af[i], bf0[n], acc[i][n], 0, 0, 0); \
    __builtin_amdgcn_s_setprio(0);                                                         \
    BARR;                                                                                  \
    /* ---- P2: A rows 64-127 kk0, B kk1 ---- */                                           \
    _Pragma("unroll") for (int i = 0; i < 4; ++i)                                          \
      af[i] = *(const short8*)(lds + (P) * 32768 + aB0 + (4 + i) * 1024);                  \
    _Pragma("unroll") for (int n = 0; n < 4; ++n)                                          \
      bf1[n] = *(const short8*)(lds + (P) * 32768 + bB1 + n * 1024);                       \
    if (SA) { GLL(pA1c0, (((P) ^ 1) * 4 + 3) * 8192 + d0);                                 \
              GLL(pA1c1, (((P) ^ 1) * 4 + 3) * 8192 + d1);                                 \
              pA1c0 += BK; pA1c1 += BK; }                                                  \
    BARR;                                                                                  \
    __builtin_amdgcn_s_setprio(1);                                                         \
    _Pragma("unroll") for (int i = 0; i < 4; ++i)                                          \
      _Pragma("unroll") for (int n = 0; n < 4; ++n)                                        \
        acc[4 + i][n] = __builtin_amdgcn_mfma_f32_16x16x32_bf16(af[i], bf0[n], acc[4 + i][n], 0, 0, 0); \
    __builtin_amdgcn_s_setprio(0);                                                         \
    BARR;                                                                                  \
    /* ---- P3: A rows 0-63 kk1 ---- */                                                    \
    _Pragma("unroll") for (int i = 0; i < 4; ++i)                                          \
      af[i] = *(const short8*)(lds + (P) * 32768 + aB1 + i * 1024);                        \
    if (SB) { GLL(pB0c0, ((P) * 4 + 0) * 8192 + d0);                                       \
              GLL(pB0c1, ((P) * 4 + 0) * 8192 + d1);                                       \
              pB0c0 += BK; pB0c1 += BK; }                                                  \
    BARR;                                                                                  \
    __builtin_amdgcn_s_setprio(1);                                                         \
    _Pragma("unroll") for (int i = 0; i < 4; ++i)                                          \
      _Pragma("unroll") for (int n = 0; n < 4; ++n)                                        \
        acc[i][n] = __builtin_amdgcn_mfma_f32_16x16x32_bf16(af[i], bf1[n], acc[i][n], 0, 0, 0); \
    __builtin_amdgcn_s_setprio(0);                                                         \
    BARR;                                                                                  \
    /* ---- P4: A rows 64-127 kk1 ---- */                                                  \
    _Pragma("unroll") for (int i = 0; i < 4; ++i)                                          \
      af[i] = *(const short8*)(lds + (P) * 32768 + aB1 + (4 + i) * 1024);                  \
    if (SB) { GLL(pB1c0, ((P) * 4 + 1) * 8192 + d0);                                       \
              GLL(pB1c1, ((P) * 4 + 1) * 8192 + d1);                                       \
              pB1c0 += BK; pB1c1 += BK; }                                                  \
    if ((VMODE) == 0) { WAITV(4); } else if ((VMODE) == 1) { WAITV(0); }                   \
    BARR;                                                                                  \
    __builtin_amdgcn_s_setprio(1);                                                         \
    _Pragma("unroll") for (int i = 0; i < 4; ++i)                                          \
      _Pragma("unroll") for (int n = 0; n < 4; ++n)                                        \
        acc[4 + i][n] = __builtin_amdgcn_mfma_f32_16x16x32_bf16(af[i], bf1[n], acc[4 + i][n], 0, 0, 0); \
    __builtin_amdgcn_s_setprio(0);                                                         \
    BARR;                                                                                  \
  } while (0)

  // main loop: tiles 0..61
  for (int it = 0; it < (NTILE - 2) / 2; ++it) {
    TILE(0, 1, 1, 0);
    TILE(1, 1, 1, 0);
  }
  TILE(0, 1, 0, 1);   // tile 62: stage A(63) only; drain everything
  TILE(1, 0, 0, 2);   // tile 63: no stage, no wait

#undef TILE
#undef GLL

  // epilogue: C/D layout col=lane&15, row=(lane>>4)*4+reg (validated R1-R3)
  const int row0 = tm * BM + wm * 128 + lk * 4;
  const int col0 = tn * BN + wn * 64 + lr;
#pragma unroll
  for (int m = 0; m < 8; ++m)
#pragma unroll
    for (int n = 0; n < 4; ++n)
#pragma unroll
      for (int rr = 0; rr < 4; ++rr)
        C[(size_t)(row0 + m * 16 + rr) * N_DIM + col0 + n * 16] = acc[m][n][rr];
}

// ---------------- Fallback: fp32 LDS-tiled GEMM reading packed weights (ws too small) ----------------
__global__ __launch_bounds__(256) void fallback_gemm(const float* __restrict__ x,
                                                     const int* __restrict__ pw,
                                                     const float* __restrict__ sc,
                                                     const float* __restrict__ zp,
                                                     float* __restrict__ out) {
  __shared__ float Xs[64][33];
  __shared__ float Ws[64][33];
  const int bid = blockIdx.x;
  const int bm = bid & 63;
  const int bn = bid >> 6;
  const int t = threadIdx.x;
  const int tx = t & 15, ty = t >> 4;
  float acc[4][4] = {};
  for (int k0 = 0; k0 < K_DIM; k0 += 32) {
    __syncthreads();
#pragma unroll
    for (int i = 0; i < 8; ++i) {
      int e = t + i * 256; int r = e >> 5, c = e & 31;
      Xs[r][c] = x[(size_t)(bm * 64 + r) * K_DIM + k0 + c];
    }
#pragma unroll
    for (int i = 0; i < 4; ++i) {
      int e = t + i * 256; int rr = e >> 4, jj = e & 15;
      int row = bn * 64 + rr;
      int v = pw[(size_t)row * KP + (k0 >> 1) + jj];
      float s = sc[row], z = zp[row];
      Ws[rr][2 * jj]     = ((float)(v & 15) - z) * s;
      Ws[rr][2 * jj + 1] = ((float)((v >> 4) & 15) - z) * s;
    }
    __syncthreads();
#pragma unroll
    for (int kk = 0; kk < 32; ++kk) {
      float a[4], b[4];
#pragma unroll
      for (int i2 = 0; i2 < 4; ++i2) a[i2] = Xs[ty * 4 + i2][kk];
#pragma unroll
      for (int j2 = 0; j2 < 4; ++j2) b[j2] = Ws[tx * 4 + j2][kk];
#pragma unroll
      for (int i2 = 0; i2 < 4; ++i2)
#pragma unroll
        for (int j2 = 0; j2 < 4; ++j2) acc[i2][j2] += a[i2] * b[j2];
    }
  }
#pragma unroll
  for (int i2 = 0; i2 < 4; ++i2)
#pragma unroll
    for (int j2 = 0; j2 < 4; ++j2)
      out[(size_t)(bm * 64 + ty * 4 + i2) * N_DIM + bn * 64 + tx * 4 + j2] = acc[i2][j2];
}

extern "C" void kernel_launch(void* const* d_in, const int* in_sizes, int n_in,
                              void* d_out, int out_size, void* d_ws, size_t ws_size,
                              hipStream_t stream) {
  const float* x  = (const float*)d_in[0];
  const int*   pw = (const int*)d_in[1];
  const float* sc = (const float*)d_in[2];
  const float* zp = (const float*)d_in[3];
  float* out = (float*)d_out;

  const size_t wb_bytes = (size_t)N_DIM * K_DIM * 2;
  const size_t xb_bytes = (size_t)M_DIM * K_DIM * 2;

  if (ws_size >= wb_bytes + xb_bytes) {
    unsigned short* wb = (unsigned short*)d_ws;
    unsigned short* xb = (unsigned short*)((char*)d_ws + wb_bytes);
    hipLaunchKernelGGL(dequant_w, dim3(2048), dim3(256), 0, stream, pw, sc, zp, wb);
    hipLaunchKernelGGL(conv_x,    dim3(2048), dim3(256), 0, stream, x, xb);
    hipLaunchKernelGGL(gemm_bt,   dim3(NWG),  dim3(512), 0, stream, xb, wb, out);
  } else {
    hipLaunchKernelGGL(fallback_gemm, dim3(64 * 172), dim3(256), 0, stream, x, pw, sc, zp, out);
  }
}